// Round 5
// baseline (752.531 us; speedup 1.0000x reference)
//
#include <hip/hip_runtime.h>
#include <math.h>

// Problem constants (from reference): B=16, T=64, H=32, W=32, C=64
constexpr int Bc = 16, Tc = 64, Hc = 32, Wc = 32, Cc = 64;
constexpr int HWC = Hc * Wc * Cc;              // 65536 = 2^16 (256 KiB plane)
constexpr long long NELEM = (long long)Bc * Tc * HWC;  // 67,108,864
constexpr float DECAY_V = 0.8f;
constexpr float VTH_BASE = 0.5f;

typedef float v4f __attribute__((ext_vector_type(4)));

// Round-5: DRAM BURST GRANULARITY. Rounds 1-4 (occupancy 2x, prefetch depth
// 1 and 4, XCD swizzle) were ALL null at ~2.4 TB/s, while float4-copy does
// 6.3 TB/s. Remaining structural difference: per t-step each block emitted
// only 2 KB contiguous per stream before a 256 KiB plane jump; ~6000
// drifting 2KB-burst streams thrash DRAM rows. Here each thread owns 16
// elems (4 x float4 at tid*4 + k*1024), so a 256-thread block owns a
// contiguous 16 KiB segment per plane: per t-step it bursts 16 KiB
// contiguous per stream (4 KiB per wave guaranteed), every instruction
// still perfectly lane-coalesced. 256 blocks = 1 block/CU (occupancy
// proved irrelevant in rounds 1/3). Loads of plane t+1 issue before the
// stores of plane t; stores grouped: s-burst then v-burst.
__global__ __launch_bounds__(256) void alif_fwd_kernel(
    const float* __restrict__ x,             // [B,T,H,W,C]
    const float* __restrict__ hp_base_step,  // scalar
    const float* __restrict__ hp_base_decay, // scalar
    const float* __restrict__ step_w_raw,    // [H,W,C]
    const float* __restrict__ decay_w_raw,   // [H,W,C]
    const float* __restrict__ gamma,         // [H,W,C]
    const float* __restrict__ beta,          // [H,W,C]
    float* __restrict__ spikes,              // [B,T,H,W,C]
    float* __restrict__ volts)               // [B,T,H,W,C]
{
    const int bk  = (int)blockIdx.x;            // 0..255
    const int b   = bk >> 4;                    // 16 blocks per batch entry
    const int seg = (bk & 15) << 12;            // *4096: segment in HWC
    const int e0  = seg + ((int)threadIdx.x << 2);  // k=0 group start

    const float base_step  = *hp_base_step;     // wave-uniform scalars
    const float base_decay = *hp_base_decay;

    // per-thread parameters for 16 elems: groups k=0..3 at e0 + k*1024
    v4f gm[4], bt[4], se[4], de[4];
#pragma unroll
    for (int k = 0; k < 4; ++k) {
        const int h = e0 + (k << 10);
        const v4f swr = *(const v4f*)(step_w_raw  + h);
        const v4f dwr = *(const v4f*)(decay_w_raw + h);
        gm[k] = *(const v4f*)(gamma + h);
        bt[k] = *(const v4f*)(beta  + h);
#pragma unroll
        for (int j = 0; j < 4; ++j) {
            // softplus / sigmoid in double, rounded to f32 -> correctly-
            // rounded f32 param path (matches numpy f32 within exp() ulp).
            float sw = (float)log1p(exp((double)swr[j]));
            float dw = (float)(1.0 / (1.0 + exp(-(double)dwr[j])));
            se[k][j] = base_step * sw;
            de[k][j] = base_decay + (1.0f - base_decay) * dw;
        }
    }

    v4f v[4], vth[4];
#pragma unroll
    for (int k = 0; k < 4; ++k) { v[k] = (v4f)0.f; vth[k] = (v4f)0.f; }

    const size_t base = (size_t)b * Tc * HWC + (size_t)e0;
    const float* xp = x      + base;
    float*       sp = spikes + base;
    float*       vp = volts  + base;

    // compute one t-step for all 16 elems from xc[0..3], then burst-store
    auto step_all = [&](const v4f* xc) {
        v4f so[4], vo[4];
#pragma unroll
        for (int k = 0; k < 4; ++k) {
#pragma unroll
            for (int j = 0; j < 4; ++j) {
                float vv      = v[k][j] * DECAY_V + (xc[k][j] * gm[k][j] + bt[k][j]);
                float vth_eff = VTH_BASE + vth[k][j];
                float s       = (vv - vth_eff > 0.0f) ? 1.0f : 0.0f;
                vo[k][j]  = vv;                      // voltage BEFORE reset
                v[k][j]   = vv - vth_eff * s;        // soft reset
                vth[k][j] = vth[k][j] * de[k][j] + s * se[k][j];
                so[k][j]  = s;
            }
        }
        // grouped bursts: 4 KiB of spikes, then 4 KiB of volts (per wave)
#pragma unroll
        for (int k = 0; k < 4; ++k)
            __builtin_nontemporal_store(so[k], (v4f*)(sp + (k << 10)));
#pragma unroll
        for (int k = 0; k < 4; ++k)
            __builtin_nontemporal_store(vo[k], (v4f*)(vp + (k << 10)));
        sp += HWC; vp += HWC;
    };

    // preload plane t=0 (4 KiB per wave in flight)
    v4f xc[4], xn[4];
#pragma unroll
    for (int k = 0; k < 4; ++k)
        xc[k] = __builtin_nontemporal_load((const v4f*)(xp + (k << 10)));

    for (int t = 0; t < Tc - 1; ++t) {
        xp += HWC;
        // issue next-plane loads BEFORE this plane's stores
#pragma unroll
        for (int k = 0; k < 4; ++k)
            xn[k] = __builtin_nontemporal_load((const v4f*)(xp + (k << 10)));
        step_all(xc);
#pragma unroll
        for (int k = 0; k < 4; ++k) xc[k] = xn[k];
    }
    step_all(xc);   // t = 63, no prefetch
}

extern "C" void kernel_launch(void* const* d_in, const int* in_sizes, int n_in,
                              void* d_out, int out_size, void* d_ws, size_t ws_size,
                              hipStream_t stream) {
    // Input order per setup_inputs():
    // 0: x, 1: hp_alpha (unused in fwd), 2: hp_base_step, 3: hp_base_decay,
    // 4: step_w_raw, 5: decay_w_raw, 6: gamma, 7: beta
    const float* x             = (const float*)d_in[0];
    const float* hp_base_step  = (const float*)d_in[2];
    const float* hp_base_decay = (const float*)d_in[3];
    const float* step_w_raw    = (const float*)d_in[4];
    const float* decay_w_raw   = (const float*)d_in[5];
    const float* gamma         = (const float*)d_in[6];
    const float* beta          = (const float*)d_in[7];

    float* spikes = (float*)d_out;           // output 0: [B,T,H,W,C]
    float* volts  = spikes + NELEM;          // output 1: [B,T,H,W,C]

    const int threads = 256;
    const int blocks  = Bc * HWC / (threads * 16);  // 256 blocks, 16 elem/thr

    alif_fwd_kernel<<<blocks, threads, 0, stream>>>(
        x, hp_base_step, hp_base_decay, step_w_raw, decay_w_raw,
        gamma, beta, spikes, volts);
}

// Round 6
// 710.751 us; speedup vs baseline: 1.0588x; 1.0588x over previous
//
#include <hip/hip_runtime.h>
#include <math.h>

// Problem constants (from reference): B=16, T=64, H=32, W=32, C=64
constexpr int Bc = 16, Tc = 64, Hc = 32, Wc = 32, Cc = 64;
constexpr int HWC = Hc * Wc * Cc;              // 65536 = 2^16
constexpr long long NELEM = (long long)Bc * Tc * HWC;  // 67,108,864
constexpr float DECAY_V = 0.8f;
constexpr float VTH_BASE = 0.5f;

typedef float v2f __attribute__((ext_vector_type(2)));

// Round-6: exact replica of the best-measured variant (round 1: 699.4 us —
// 2 floats/thread, 2048 blocks = 8 blocks/CU = 32 waves/CU, 1-deep register
// prefetch, unroll 8) with ONE variable changed: nontemporal hints REMOVED.
// Mechanism under test: gfx950 'nt' stores bypass TCC allocation; normal
// cached writes let TCC/MALL coalesce full-line writebacks and schedule
// DRAM writes in batches (the 6.2 TB/s poison fill uses normal writes).
// Pre-committed read: null (695-705) => kernel is at its mixed-stream
// floor and dur_us is dominated by fixed harness cost => ROOFLINE.
__global__ __launch_bounds__(256) void alif_fwd_kernel(
    const float* __restrict__ x,             // [B,T,H,W,C]
    const float* __restrict__ hp_base_step,  // scalar
    const float* __restrict__ hp_base_decay, // scalar
    const float* __restrict__ step_w_raw,    // [H,W,C]
    const float* __restrict__ decay_w_raw,   // [H,W,C]
    const float* __restrict__ gamma,         // [H,W,C]
    const float* __restrict__ beta,          // [H,W,C]
    float* __restrict__ spikes,              // [B,T,H,W,C]
    float* __restrict__ volts)               // [B,T,H,W,C]
{
    const int tid = blockIdx.x * blockDim.x + threadIdx.x;  // 0 .. 524287
    const int c2  = tid << 1;              // element index into [B,H,W,C]
    const int b   = c2 >> 16;              // / HWC
    const int hwc = c2 & (HWC - 1);        // % HWC

    const float base_step  = *hp_base_step;   // wave-uniform scalar loads
    const float base_decay = *hp_base_decay;

    const v2f swr = *(const v2f*)(step_w_raw  + hwc);
    const v2f dwr = *(const v2f*)(decay_w_raw + hwc);
    const v2f gm2 = *(const v2f*)(gamma       + hwc);
    const v2f bt2 = *(const v2f*)(beta        + hwc);

    float gm[2]    = {gm2.x, gm2.y};
    float bt[2]    = {bt2.x, bt2.y};
    float swr_a[2] = {swr.x, swr.y};
    float dwr_a[2] = {dwr.x, dwr.y};

    float step_eff[2], decay_eff[2];
    float v[2]   = {0.f, 0.f};
    float vth[2] = {0.f, 0.f};

#pragma unroll
    for (int j = 0; j < 2; ++j) {
        // softplus / sigmoid in double, rounded to f32 -> correctly-rounded
        // f32 param path (matches numpy f32 to within its own exp() ulp).
        float sw = (float)log1p(exp((double)swr_a[j]));
        float dw = (float)(1.0 / (1.0 + exp(-(double)dwr_a[j])));
        step_eff[j]  = base_step * sw;
        decay_eff[j] = base_decay + (1.0f - base_decay) * dw;
    }

    const size_t base = (size_t)b * Tc * HWC + (size_t)hwc;
    const float* xp = x      + base;
    float*       sp = spikes + base;
    float*       vp = volts  + base;

    // software pipeline: x[t+1] load is always in flight during step t
    v2f xcur = *(const v2f*)xp;

#pragma unroll 8
    for (int t = 0; t < Tc; ++t) {
        // branch-free prefetch address (clamped so t=63 re-reads row 63
        // instead of running off the buffer); load issued before compute.
        const float* xnp = xp + ((t + 1 < Tc) ? HWC : 0);
        v2f xnext = *(const v2f*)xnp;

        float xin[2] = {xcur.x, xcur.y};
        float sarr[2], varr[2];
#pragma unroll
        for (int j = 0; j < 2; ++j) {
            float vv      = v[j] * DECAY_V + (xin[j] * gm[j] + bt[j]);
            float vth_eff = VTH_BASE + vth[j];
            float s       = (vv - vth_eff > 0.0f) ? 1.0f : 0.0f;
            varr[j] = vv;                       // voltage BEFORE reset
            v[j]    = vv - vth_eff * s;         // soft reset
            vth[j]  = vth[j] * decay_eff[j] + s * step_eff[j];
            sarr[j] = s;
        }
        v2f so = {sarr[0], sarr[1]};
        v2f vo = {varr[0], varr[1]};
        *(v2f*)sp = so;
        *(v2f*)vp = vo;

        xcur = xnext;
        xp = xnp; sp += HWC; vp += HWC;
    }
}

extern "C" void kernel_launch(void* const* d_in, const int* in_sizes, int n_in,
                              void* d_out, int out_size, void* d_ws, size_t ws_size,
                              hipStream_t stream) {
    // Input order per setup_inputs():
    // 0: x, 1: hp_alpha (unused in fwd), 2: hp_base_step, 3: hp_base_decay,
    // 4: step_w_raw, 5: decay_w_raw, 6: gamma, 7: beta
    const float* x             = (const float*)d_in[0];
    const float* hp_base_step  = (const float*)d_in[2];
    const float* hp_base_decay = (const float*)d_in[3];
    const float* step_w_raw    = (const float*)d_in[4];
    const float* decay_w_raw   = (const float*)d_in[5];
    const float* gamma         = (const float*)d_in[6];
    const float* beta          = (const float*)d_in[7];

    float* spikes = (float*)d_out;           // output 0: [B,T,H,W,C]
    float* volts  = spikes + NELEM;          // output 1: [B,T,H,W,C]

    const int threads = 256;
    const int total   = Bc * HWC / 2;        // 524,288 threads
    const int blocks  = total / threads;     // 2048 blocks -> 8 blocks/CU

    alif_fwd_kernel<<<blocks, threads, 0, stream>>>(
        x, hp_base_step, hp_base_decay, step_w_raw, decay_w_raw,
        gamma, beta, spikes, volts);
}